// Round 4
// baseline (646.508 us; speedup 1.0000x reference)
//
#include <hip/hip_runtime.h>
#include <cstdint>
#include <cstddef>

// ---------------------------------------------------------------------------
// GCN 2-layer encoder.  Pipeline per launch:
//   1. bin edges by dst>>7 (128 nodes/bin) into a bin-contiguous buffer
//   2. per-bin LDS counters -> degree, dis = rsqrt(deg+1)
//   3. exclusive scan -> CSR rowptr; per-bin LDS cursors -> col[] + wgt[]
//   4. h1 = x @ W1                (fp32 GEMM, W staged in LDS by 128-row chunks)
//   5. out1 = relu(Agg(h1) + b1)  (4-edges-per-wave float4 gather)
//   6. h2 = out1 @ W2 ; d_out = Agg(h2) + b2
// Self-loops contribute dis[i]^2 * h[i] directly (not stored in CSR).
// ---------------------------------------------------------------------------

#define BIN_SHIFT 7
#define BIN_NODES 128
#define MAX_BINS 1024

__global__ void zero_int(int* __restrict__ p, int n) {
  int i = blockIdx.x * blockDim.x + threadIdx.x;
  if (i < n) p[i] = 0;
}

// --- pass A: histogram of edges per bin -------------------------------------
__global__ __launch_bounds__(256) void bin_count(const int* __restrict__ dst, int E, int nbins,
                                                 int* __restrict__ binCnt) {
  __shared__ int h[MAX_BINS];
  for (int i = threadIdx.x; i < nbins; i += 256) h[i] = 0;
  __syncthreads();
  int stride = gridDim.x * 256;
  for (int e = blockIdx.x * 256 + threadIdx.x; e < E; e += stride)
    atomicAdd(&h[dst[e] >> BIN_SHIFT], 1);
  __syncthreads();
  for (int i = threadIdx.x; i < nbins; i += 256)
    if (h[i]) atomicAdd(&binCnt[i], h[i]);
}

// --- exclusive scan over <=1024 bins, single block --------------------------
__global__ __launch_bounds__(256) void bin_scan(const int* __restrict__ binCnt, int nbins, int E,
                                                int* __restrict__ binStart,
                                                int* __restrict__ binCursor) {
  __shared__ int s[256];
  int t = threadIdx.x;
  int c[4];
  int sum = 0;
#pragma unroll
  for (int i = 0; i < 4; i++) {
    int idx = t * 4 + i;
    c[i] = (idx < nbins) ? binCnt[idx] : 0;
    sum += c[i];
  }
  int v = sum;
  s[t] = v;
  __syncthreads();
  for (int d = 1; d < 256; d <<= 1) {
    int add = (t >= d) ? s[t - d] : 0;
    __syncthreads();
    s[t] += add;
    __syncthreads();
  }
  int run = s[t] - v;  // exclusive prefix
#pragma unroll
  for (int i = 0; i < 4; i++) {
    int idx = t * 4 + i;
    if (idx < nbins) {
      binStart[idx] = run;
      binCursor[idx] = run;
      run += c[i];
    }
  }
  if (t == 0) binStart[nbins] = E;
}

// --- pass B: partition (src,dst) into bin-contiguous binbuf -----------------
__global__ __launch_bounds__(256) void bin_fill(const int* __restrict__ src,
                                                const int* __restrict__ dst, int E, int nbins,
                                                int* __restrict__ binCursor,
                                                int2* __restrict__ binbuf) {
  __shared__ int h[MAX_BINS];
  __shared__ int lbase[MAX_BINS];
  __shared__ int lcnt[MAX_BINS];
  int chunk = (E + gridDim.x - 1) / gridDim.x;
  int c0 = blockIdx.x * chunk;
  int c1 = min(E, c0 + chunk);
  for (int i = threadIdx.x; i < nbins; i += 256) {
    h[i] = 0;
    lcnt[i] = 0;
  }
  __syncthreads();
  for (int e = c0 + threadIdx.x; e < c1; e += 256) atomicAdd(&h[dst[e] >> BIN_SHIFT], 1);
  __syncthreads();
  for (int i = threadIdx.x; i < nbins; i += 256)
    lbase[i] = h[i] ? atomicAdd(&binCursor[i], h[i]) : 0;
  __syncthreads();
  for (int e = c0 + threadIdx.x; e < c1; e += 256) {
    int d = dst[e];
    int b = d >> BIN_SHIFT;
    int idx = lbase[b] + atomicAdd(&lcnt[b], 1);
    binbuf[idx] = make_int2(src[e], d);
  }
}

// --- pass C: per-bin node degree + dis --------------------------------------
__global__ __launch_bounds__(256) void node_count_dis(const int2* __restrict__ binbuf,
                                                      const int* __restrict__ binStart, int N,
                                                      int* __restrict__ count,
                                                      float* __restrict__ dis) {
  __shared__ int cnt[BIN_NODES];
  int b = blockIdx.x;
  int nodeBase = b << BIN_SHIFT;
  if (threadIdx.x < BIN_NODES) cnt[threadIdx.x] = 0;
  __syncthreads();
  int s0 = binStart[b], s1 = binStart[b + 1];
  for (int i = s0 + threadIdx.x; i < s1; i += 256) atomicAdd(&cnt[binbuf[i].y - nodeBase], 1);
  __syncthreads();
  if (threadIdx.x < BIN_NODES) {
    int node = nodeBase + threadIdx.x;
    if (node < N) {
      int c = cnt[threadIdx.x];
      count[node] = c;
      dis[node] = rsqrtf((float)(c + 1));  // +1 self loop
    }
  }
}

// --- hierarchical exclusive scan over count[0..N) -> rowptr ------------------
__global__ void scan_partial(const int* __restrict__ count, int* __restrict__ bsum, int N) {
  __shared__ int s[256];
  int t = threadIdx.x, b = blockIdx.x;
  int base = b * 1024 + t * 4;
  int sum = 0;
#pragma unroll
  for (int i = 0; i < 4; i++) sum += (base + i < N) ? count[base + i] : 0;
  s[t] = sum;
  __syncthreads();
  for (int d = 128; d > 0; d >>= 1) {
    if (t < d) s[t] += s[t + d];
    __syncthreads();
  }
  if (t == 0) bsum[b] = s[0];
}

__global__ void scan_blocksums(int* __restrict__ bsum, int nb) {
  __shared__ int s[256];
  int t = threadIdx.x;
  int v = (t < nb) ? bsum[t] : 0;
  s[t] = v;
  __syncthreads();
  for (int d = 1; d < 256; d <<= 1) {
    int add = (t >= d) ? s[t - d] : 0;
    __syncthreads();
    s[t] += add;
    __syncthreads();
  }
  if (t < nb) bsum[t] = s[t] - v;  // exclusive
}

__global__ void scan_final(const int* __restrict__ count, const int* __restrict__ bsum,
                           int* __restrict__ rowptr, int N, int E) {
  __shared__ int s[256];
  int t = threadIdx.x, b = blockIdx.x;
  int base = b * 1024 + t * 4;
  int c[4];
  int sum = 0;
#pragma unroll
  for (int i = 0; i < 4; i++) {
    c[i] = (base + i < N) ? count[base + i] : 0;
    sum += c[i];
  }
  int v = sum;
  s[t] = v;
  __syncthreads();
  for (int d = 1; d < 256; d <<= 1) {
    int add = (t >= d) ? s[t - d] : 0;
    __syncthreads();
    s[t] += add;
    __syncthreads();
  }
  int run = bsum[b] + (s[t] - v);
#pragma unroll
  for (int i = 0; i < 4; i++) {
    if (base + i < N) {
      rowptr[base + i] = run;
      run += c[i];
    }
  }
  if (b == 0 && t == 0) rowptr[N] = E;
}

// --- pass D: per-bin CSR fill (writes confined to ~16 KB window) ------------
__global__ __launch_bounds__(256) void csr_fill(const int2* __restrict__ binbuf,
                                                const int* __restrict__ binStart,
                                                const int* __restrict__ rowptr,
                                                const float* __restrict__ dis, int N,
                                                int* __restrict__ col, float* __restrict__ wgt) {
  __shared__ int cur[BIN_NODES];
  __shared__ float dloc[BIN_NODES];
  int b = blockIdx.x;
  int nodeBase = b << BIN_SHIFT;
  if (threadIdx.x < BIN_NODES) {
    int node = nodeBase + threadIdx.x;
    cur[threadIdx.x] = (node < N) ? rowptr[node] : 0;
    dloc[threadIdx.x] = (node < N) ? dis[node] : 0.f;
  }
  __syncthreads();
  int s0 = binStart[b], s1 = binStart[b + 1];
  for (int i = s0 + threadIdx.x; i < s1; i += 256) {
    int2 e = binbuf[i];
    int dl = e.y - nodeBase;
    int slot = atomicAdd(&cur[dl], 1);
    col[slot] = e.x;
    wgt[slot] = dis[e.x] * dloc[dl];
  }
}

// --- GEMM: C[M][64] = A[M][K] @ W[K][64], W staged in LDS by CHUNK rows -----
// CHUNK=128 -> 32 KB LDS -> >=4 blocks/CU (vs 64 KB monolithic = 2 blocks/CU,
// 17% occupancy, VALUBusy 27% in round 3).  W re-reads come from L2 (cheap).
template <int K>
__global__ __launch_bounds__(256, 4) void gemm64(const float* __restrict__ A,
                                                 const float* __restrict__ W,
                                                 float* __restrict__ C, int M) {
  constexpr int CHUNK = (K > 128) ? 128 : K;
  __shared__ float4 wlds[CHUNK * 16];  // CHUNK rows x 16 float4 (64 cols)

  const int c0 = threadIdx.x & 15;  // which float4 of the 64-col row
  const int rq = threadIdx.x >> 4;  // row quad within block
  const int r0 = blockIdx.x * 64 + rq * 4;

  float4 acc[4];
#pragma unroll
  for (int i = 0; i < 4; i++) acc[i] = make_float4(0.f, 0.f, 0.f, 0.f);
  size_t aoff[4];
  bool ok[4];
#pragma unroll
  for (int i = 0; i < 4; i++) {
    int r = r0 + i;
    ok[i] = (r < M);
    aoff[i] = (size_t)(ok[i] ? r : (M - 1)) * K;  // clamp: no OOB, result discarded
  }

  for (int kc = 0; kc < K; kc += CHUNK) {
    {  // stage this W chunk
      const float4* W4 = (const float4*)W + (size_t)kc * 16;
      for (int i = threadIdx.x; i < CHUNK * 16; i += 256) wlds[i] = W4[i];
    }
    __syncthreads();

#pragma unroll 2
    for (int k = 0; k < CHUNK; k += 4) {
      float4 xv[4];
#pragma unroll
      for (int i = 0; i < 4; i++) xv[i] = *(const float4*)(A + aoff[i] + kc + k);
      float4 w0 = wlds[(k + 0) * 16 + c0];
      float4 w1 = wlds[(k + 1) * 16 + c0];
      float4 w2 = wlds[(k + 2) * 16 + c0];
      float4 w3 = wlds[(k + 3) * 16 + c0];
#pragma unroll
      for (int i = 0; i < 4; i++) {
        acc[i].x += xv[i].x * w0.x + xv[i].y * w1.x + xv[i].z * w2.x + xv[i].w * w3.x;
        acc[i].y += xv[i].x * w0.y + xv[i].y * w1.y + xv[i].z * w2.y + xv[i].w * w3.y;
        acc[i].z += xv[i].x * w0.z + xv[i].y * w1.z + xv[i].z * w2.z + xv[i].w * w3.z;
        acc[i].w += xv[i].x * w0.w + xv[i].y * w1.w + xv[i].z * w2.w + xv[i].w * w3.w;
      }
    }
    __syncthreads();  // all waves participate (no early return above)
  }
#pragma unroll
  for (int i = 0; i < 4; i++)
    if (ok[i]) *(float4*)&C[(size_t)(r0 + i) * 64 + c0 * 4] = acc[i];
}

// --- aggregation: wave per node, FOUR edges per wave in flight --------------
// Lane layout: quarter = lane>>4 picks the edge of a 4-edge group, sub =
// lane&15 picks the float4 of the 64-float h-row (16 x 16 B = 256 B/edge).
// 4-way unroll => 16 independent 256 B gathers in flight per wave.
__global__ __launch_bounds__(256) void agg_kernel(
    const float4* __restrict__ h, const int* __restrict__ rowptr, const int* __restrict__ col,
    const float* __restrict__ wgt, const float* __restrict__ dis, const float* __restrict__ bias,
    float4* __restrict__ out, int N, int relu) {
  int wid = (blockIdx.x * blockDim.x + threadIdx.x) >> 6;
  if (wid >= N) return;
  int lane = threadIdx.x & 63;
  int sub = lane & 15;      // float4 index within the 64-float row
  int quarter = lane >> 4;  // which edge of the 4-group

  int start = rowptr[wid], end = rowptr[wid + 1];
  float di = dis[wid];

  float4 a0 = make_float4(0.f, 0.f, 0.f, 0.f), a1 = a0, a2 = a0, a3 = a0;
  {  // self-loop term (quarter 0 only; quarters are summed at the end)
    float4 self = h[(size_t)wid * 16 + sub];
    if (quarter == 0) {
      a0.x = di * di * self.x;
      a0.y = di * di * self.y;
      a0.z = di * di * self.z;
      a0.w = di * di * self.w;
    }
  }

  for (int base = start; base < end; base += 64) {
    int e = base + lane;
    int sj = 0;
    float wj = 0.f;
    if (e < end) {
      sj = col[e];
      wj = wgt[e];
    }
    int cnt = end - base;
    if (cnt > 64) cnt = 64;
    int rounds = (cnt + 3) >> 2;  // 4-edge groups in this chunk
    int t = 0;
    for (; t + 4 <= rounds; t += 4) {
      int i0 = 4 * t + quarter;
      int s0 = __shfl(sj, i0), s1 = __shfl(sj, i0 + 4), s2 = __shfl(sj, i0 + 8),
          s3 = __shfl(sj, i0 + 12);
      float w0 = __shfl(wj, i0), w1 = __shfl(wj, i0 + 4), w2 = __shfl(wj, i0 + 8),
            w3 = __shfl(wj, i0 + 12);
      float4 g0 = h[(size_t)s0 * 16 + sub];
      float4 g1 = h[(size_t)s1 * 16 + sub];
      float4 g2 = h[(size_t)s2 * 16 + sub];
      float4 g3 = h[(size_t)s3 * 16 + sub];
      a0.x += w0 * g0.x; a0.y += w0 * g0.y; a0.z += w0 * g0.z; a0.w += w0 * g0.w;
      a1.x += w1 * g1.x; a1.y += w1 * g1.y; a1.z += w1 * g1.z; a1.w += w1 * g1.w;
      a2.x += w2 * g2.x; a2.y += w2 * g2.y; a2.z += w2 * g2.z; a2.w += w2 * g2.w;
      a3.x += w3 * g3.x; a3.y += w3 * g3.y; a3.z += w3 * g3.z; a3.w += w3 * g3.w;
    }
    for (; t < rounds; t++) {
      int i0 = 4 * t + quarter;  // may exceed cnt-1 for tail quarters: wj there is 0
      int s0 = __shfl(sj, i0);
      float w0 = __shfl(wj, i0);
      float4 g0 = h[(size_t)s0 * 16 + sub];
      a0.x += w0 * g0.x; a0.y += w0 * g0.y; a0.z += w0 * g0.z; a0.w += w0 * g0.w;
    }
  }

  float sx = (a0.x + a1.x) + (a2.x + a3.x);
  float sy = (a0.y + a1.y) + (a2.y + a3.y);
  float sz = (a0.z + a1.z) + (a2.z + a3.z);
  float sw = (a0.w + a1.w) + (a2.w + a3.w);
  // fold quarters: lanes sub+16k -> lane sub
  sx += __shfl_down(sx, 32); sy += __shfl_down(sy, 32);
  sz += __shfl_down(sz, 32); sw += __shfl_down(sw, 32);
  sx += __shfl_down(sx, 16); sy += __shfl_down(sy, 16);
  sz += __shfl_down(sz, 16); sw += __shfl_down(sw, 16);
  if (quarter == 0) {
    float4 bv = ((const float4*)bias)[sub];
    float ox = sx + bv.x, oy = sy + bv.y, oz = sz + bv.z, ow = sw + bv.w;
    if (relu) {
      ox = fmaxf(ox, 0.f);
      oy = fmaxf(oy, 0.f);
      oz = fmaxf(oz, 0.f);
      ow = fmaxf(ow, 0.f);
    }
    out[(size_t)wid * 16 + sub] = make_float4(ox, oy, oz, ow);
  }
}

// ---------------------------------------------------------------------------
extern "C" void kernel_launch(void* const* d_in, const int* in_sizes, int n_in,
                              void* d_out, int out_size, void* d_ws, size_t ws_size,
                              hipStream_t stream) {
  const float* x = (const float*)d_in[0];
  const int* ei = (const int*)d_in[1];
  const float* W1 = (const float*)d_in[2];
  const float* b1 = (const float*)d_in[3];
  const float* W2 = (const float*)d_in[4];
  const float* b2 = (const float*)d_in[5];

  const int IN = 256;
  const int E = in_sizes[1] / 2;
  const int N = in_sizes[0] / IN;
  const int* src = ei;      // edge_index[0]
  const int* dst = ei + E;  // edge_index[1]
  const int nbins = (N + BIN_NODES - 1) >> BIN_SHIFT;

  // workspace carve-up (256B aligned)
  char* ws = (char*)d_ws;
  size_t off = 0;
  auto alloc = [&](size_t bytes) -> void* {
    void* p = ws + off;
    off += (bytes + 255) & ~(size_t)255;
    return p;
  };
  int* count = (int*)alloc((size_t)N * 4);
  int* rowptr = (int*)alloc((size_t)(N + 1) * 4);
  float* dis = (float*)alloc((size_t)N * 4);
  int* bsum = (int*)alloc(4096);
  int* binCnt = (int*)alloc(MAX_BINS * 4);
  int* binStart = (int*)alloc((MAX_BINS + 1) * 4);
  int* binCursor = (int*)alloc(MAX_BINS * 4);
  int* col = (int*)alloc((size_t)E * 4);
  float* wgt = (float*)alloc((size_t)E * 4);
  // binbuf (E int2) aliases h (N*64 fp32): binbuf dead once csr_fill is done,
  // h first written by gemm1 afterwards.  25.6 MB each.
  size_t big = ((size_t)E * 8 > (size_t)N * 256) ? (size_t)E * 8 : (size_t)N * 256;
  int2* binbuf = (int2*)alloc(big);
  float* h = (float*)binbuf;
  float* out1 = (float*)d_out;  // layer-1 output staged in d_out
  float* outf = (float*)d_out;

  const int tb = 256;
  const int nb = (N + 1023) / 1024;

  zero_int<<<(nbins + tb - 1) / tb, tb, 0, stream>>>(binCnt, nbins);
  bin_count<<<256, 256, 0, stream>>>(dst, E, nbins, binCnt);
  bin_scan<<<1, 256, 0, stream>>>(binCnt, nbins, E, binStart, binCursor);
  bin_fill<<<256, 256, 0, stream>>>(src, dst, E, nbins, binCursor, binbuf);
  node_count_dis<<<nbins, 256, 0, stream>>>(binbuf, binStart, N, count, dis);
  scan_partial<<<nb, 256, 0, stream>>>(count, bsum, N);
  scan_blocksums<<<1, 256, 0, stream>>>(bsum, nb);
  scan_final<<<nb, 256, 0, stream>>>(count, bsum, rowptr, N, E);
  csr_fill<<<nbins, 256, 0, stream>>>(binbuf, binStart, rowptr, dis, N, col, wgt);

  gemm64<256><<<(N + 63) / 64, 256, 0, stream>>>(x, W1, h, N);
  agg_kernel<<<(N + 3) / 4, 256, 0, stream>>>((const float4*)h, rowptr, col, wgt, dis, b1,
                                              (float4*)out1, N, 1);
  gemm64<64><<<(N + 63) / 64, 256, 0, stream>>>(out1, W2, h, N);
  agg_kernel<<<(N + 3) / 4, 256, 0, stream>>>((const float4*)h, rowptr, col, wgt, dis, b2,
                                              (float4*)outf, N, 0);
}

// Round 5
// 540.602 us; speedup vs baseline: 1.1959x; 1.1959x over previous
//
#include <hip/hip_runtime.h>
#include <cstdint>
#include <cstddef>

// ---------------------------------------------------------------------------
// GCN 2-layer encoder.  Pipeline per launch:
//   1. bin edges by dst>>7 into a bin-contiguous PACKED buffer ((dl<<17)|src)
//   2. per-bin LDS counters -> degree, dis = rsqrt(deg+1)
//   3. exclusive scan -> CSR rowptr; per-bin LDS cursors -> col[] + wgt[]
//   4. h1 = bf16(x @ W1)          (fp32 GEMM, W staged in LDS, bf16 epilogue)
//   5. out1 = bf16(relu(Agg(h1) + b1))   (4-edges-per-wave bf16 gather)
//   6. h2 = bf16(out1 @ W2) ; d_out = Agg(h2) + b2  (fp32 out)
// All accumulation in fp32; only the h/out1 tables are bf16 (halves the
// bytes on the L2-miss-bound gather path).  Self-loops contribute
// dis[i]^2 * h[i] directly (not stored in CSR).
// ---------------------------------------------------------------------------

#define BIN_SHIFT 7
#define BIN_NODES 128
#define MAX_BINS 1024
#define SRC_BITS 17
#define SRC_MASK ((1 << SRC_BITS) - 1)

typedef unsigned short ushort_t;

__device__ __forceinline__ float4 bfq2f4(uint2 p) {  // 4 packed bf16 -> fp32 (exact)
  float4 r;
  r.x = __uint_as_float(p.x << 16);
  r.y = __uint_as_float(p.x & 0xFFFF0000u);
  r.z = __uint_as_float(p.y << 16);
  r.w = __uint_as_float(p.y & 0xFFFF0000u);
  return r;
}
__device__ __forceinline__ unsigned f2bf(float f) {  // fp32 -> bf16 bits, RNE
  unsigned u = __float_as_uint(f);
  return (u + 0x7FFFu + ((u >> 16) & 1u)) >> 16;
}
__device__ __forceinline__ uint2 f42bfq(float4 f) {
  uint2 r;
  r.x = f2bf(f.x) | (f2bf(f.y) << 16);
  r.y = f2bf(f.z) | (f2bf(f.w) << 16);
  return r;
}

__global__ void zero_int(int* __restrict__ p, int n) {
  int i = blockIdx.x * blockDim.x + threadIdx.x;
  if (i < n) p[i] = 0;
}

// --- pass A: histogram of edges per bin -------------------------------------
__global__ __launch_bounds__(256) void bin_count(const int* __restrict__ dst, int E, int nbins,
                                                 int* __restrict__ binCnt) {
  __shared__ int h[MAX_BINS];
  for (int i = threadIdx.x; i < nbins; i += 256) h[i] = 0;
  __syncthreads();
  int stride = gridDim.x * 256;
  for (int e = blockIdx.x * 256 + threadIdx.x; e < E; e += stride)
    atomicAdd(&h[dst[e] >> BIN_SHIFT], 1);
  __syncthreads();
  for (int i = threadIdx.x; i < nbins; i += 256)
    if (h[i]) atomicAdd(&binCnt[i], h[i]);
}

// --- exclusive scan over <=1024 bins, single block --------------------------
__global__ __launch_bounds__(256) void bin_scan(const int* __restrict__ binCnt, int nbins, int E,
                                                int* __restrict__ binStart,
                                                int* __restrict__ binCursor) {
  __shared__ int s[256];
  int t = threadIdx.x;
  int c[4];
  int sum = 0;
#pragma unroll
  for (int i = 0; i < 4; i++) {
    int idx = t * 4 + i;
    c[i] = (idx < nbins) ? binCnt[idx] : 0;
    sum += c[i];
  }
  int v = sum;
  s[t] = v;
  __syncthreads();
  for (int d = 1; d < 256; d <<= 1) {
    int add = (t >= d) ? s[t - d] : 0;
    __syncthreads();
    s[t] += add;
    __syncthreads();
  }
  int run = s[t] - v;  // exclusive prefix
#pragma unroll
  for (int i = 0; i < 4; i++) {
    int idx = t * 4 + i;
    if (idx < nbins) {
      binStart[idx] = run;
      binCursor[idx] = run;
      run += c[i];
    }
  }
  if (t == 0) binStart[nbins] = E;
}

// --- pass B: partition packed (dl<<17)|src into bin-contiguous binbuf -------
__global__ __launch_bounds__(256) void bin_fill(const int* __restrict__ src,
                                                const int* __restrict__ dst, int E, int nbins,
                                                int* __restrict__ binCursor,
                                                unsigned* __restrict__ binbuf) {
  __shared__ int h[MAX_BINS];
  __shared__ int lbase[MAX_BINS];
  __shared__ int lcnt[MAX_BINS];
  int chunk = (E + gridDim.x - 1) / gridDim.x;
  int c0 = blockIdx.x * chunk;
  int c1 = min(E, c0 + chunk);
  for (int i = threadIdx.x; i < nbins; i += 256) {
    h[i] = 0;
    lcnt[i] = 0;
  }
  __syncthreads();
  for (int e = c0 + threadIdx.x; e < c1; e += 256) atomicAdd(&h[dst[e] >> BIN_SHIFT], 1);
  __syncthreads();
  for (int i = threadIdx.x; i < nbins; i += 256)
    lbase[i] = h[i] ? atomicAdd(&binCursor[i], h[i]) : 0;
  __syncthreads();
  for (int e = c0 + threadIdx.x; e < c1; e += 256) {
    int d = dst[e];
    int b = d >> BIN_SHIFT;
    int idx = lbase[b] + atomicAdd(&lcnt[b], 1);
    binbuf[idx] = ((unsigned)(d & (BIN_NODES - 1)) << SRC_BITS) | (unsigned)src[e];
  }
}

// --- pass C: per-bin node degree + dis --------------------------------------
__global__ __launch_bounds__(256) void node_count_dis(const unsigned* __restrict__ binbuf,
                                                      const int* __restrict__ binStart, int N,
                                                      int* __restrict__ count,
                                                      float* __restrict__ dis) {
  __shared__ int cnt[BIN_NODES];
  int b = blockIdx.x;
  int nodeBase = b << BIN_SHIFT;
  if (threadIdx.x < BIN_NODES) cnt[threadIdx.x] = 0;
  __syncthreads();
  int s0 = binStart[b], s1 = binStart[b + 1];
  for (int i = s0 + threadIdx.x; i < s1; i += 256) atomicAdd(&cnt[binbuf[i] >> SRC_BITS], 1);
  __syncthreads();
  if (threadIdx.x < BIN_NODES) {
    int node = nodeBase + threadIdx.x;
    if (node < N) {
      int c = cnt[threadIdx.x];
      count[node] = c;
      dis[node] = rsqrtf((float)(c + 1));  // +1 self loop
    }
  }
}

// --- hierarchical exclusive scan over count[0..N) -> rowptr ------------------
__global__ void scan_partial(const int* __restrict__ count, int* __restrict__ bsum, int N) {
  __shared__ int s[256];
  int t = threadIdx.x, b = blockIdx.x;
  int base = b * 1024 + t * 4;
  int sum = 0;
#pragma unroll
  for (int i = 0; i < 4; i++) sum += (base + i < N) ? count[base + i] : 0;
  s[t] = sum;
  __syncthreads();
  for (int d = 128; d > 0; d >>= 1) {
    if (t < d) s[t] += s[t + d];
    __syncthreads();
  }
  if (t == 0) bsum[b] = s[0];
}

__global__ void scan_blocksums(int* __restrict__ bsum, int nb) {
  __shared__ int s[256];
  int t = threadIdx.x;
  int v = (t < nb) ? bsum[t] : 0;
  s[t] = v;
  __syncthreads();
  for (int d = 1; d < 256; d <<= 1) {
    int add = (t >= d) ? s[t - d] : 0;
    __syncthreads();
    s[t] += add;
    __syncthreads();
  }
  if (t < nb) bsum[t] = s[t] - v;  // exclusive
}

__global__ void scan_final(const int* __restrict__ count, const int* __restrict__ bsum,
                           int* __restrict__ rowptr, int N, int E) {
  __shared__ int s[256];
  int t = threadIdx.x, b = blockIdx.x;
  int base = b * 1024 + t * 4;
  int c[4];
  int sum = 0;
#pragma unroll
  for (int i = 0; i < 4; i++) {
    c[i] = (base + i < N) ? count[base + i] : 0;
    sum += c[i];
  }
  int v = sum;
  s[t] = v;
  __syncthreads();
  for (int d = 1; d < 256; d <<= 1) {
    int add = (t >= d) ? s[t - d] : 0;
    __syncthreads();
    s[t] += add;
    __syncthreads();
  }
  int run = bsum[b] + (s[t] - v);
#pragma unroll
  for (int i = 0; i < 4; i++) {
    if (base + i < N) {
      rowptr[base + i] = run;
      run += c[i];
    }
  }
  if (b == 0 && t == 0) rowptr[N] = E;
}

// --- pass D: per-bin CSR fill (writes confined to ~32 KB window) ------------
__global__ __launch_bounds__(256) void csr_fill(const unsigned* __restrict__ binbuf,
                                                const int* __restrict__ binStart,
                                                const int* __restrict__ rowptr,
                                                const float* __restrict__ dis, int N,
                                                int* __restrict__ col, float* __restrict__ wgt) {
  __shared__ int cur[BIN_NODES];
  __shared__ float dloc[BIN_NODES];
  int b = blockIdx.x;
  int nodeBase = b << BIN_SHIFT;
  if (threadIdx.x < BIN_NODES) {
    int node = nodeBase + threadIdx.x;
    cur[threadIdx.x] = (node < N) ? rowptr[node] : 0;
    dloc[threadIdx.x] = (node < N) ? dis[node] : 0.f;
  }
  __syncthreads();
  int s0 = binStart[b], s1 = binStart[b + 1];
  for (int i = s0 + threadIdx.x; i < s1; i += 256) {
    unsigned e = binbuf[i];
    int dl = e >> SRC_BITS;
    int sidx = e & SRC_MASK;
    int slot = atomicAdd(&cur[dl], 1);
    col[slot] = sidx;
    wgt[slot] = dis[sidx] * dloc[dl];
  }
}

// --- GEMM: Cbf16[M][64] = A[M][K] @ W[K][64], W staged in LDS ---------------
// ABF16 selects bf16 A (layer 2's out1); accumulation always fp32.
// CHUNK<=128 rows of W -> <=32 KB LDS -> 4+ blocks/CU.
template <int K, bool ABF16>
__global__ __launch_bounds__(256, 4) void gemm64(const void* __restrict__ Av,
                                                 const float* __restrict__ W,
                                                 uint2* __restrict__ Cb, int M) {
  constexpr int CHUNK = (K > 128) ? 128 : K;
  __shared__ float4 wlds[CHUNK * 16];  // CHUNK rows x 16 float4 (64 cols)

  const int c0 = threadIdx.x & 15;  // which float4 of the 64-col row
  const int rq = threadIdx.x >> 4;  // row quad within block
  const int r0 = blockIdx.x * 64 + rq * 4;

  float4 acc[4];
#pragma unroll
  for (int i = 0; i < 4; i++) acc[i] = make_float4(0.f, 0.f, 0.f, 0.f);
  size_t aoff[4];
  bool ok[4];
#pragma unroll
  for (int i = 0; i < 4; i++) {
    int r = r0 + i;
    ok[i] = (r < M);
    aoff[i] = (size_t)(ok[i] ? r : (M - 1)) * K;  // clamp: no OOB, result discarded
  }

  for (int kc = 0; kc < K; kc += CHUNK) {
    {  // stage this W chunk
      const float4* W4 = (const float4*)W + (size_t)kc * 16;
      for (int i = threadIdx.x; i < CHUNK * 16; i += 256) wlds[i] = W4[i];
    }
    __syncthreads();

#pragma unroll 2
    for (int k = 0; k < CHUNK; k += 4) {
      float4 xv[4];
#pragma unroll
      for (int i = 0; i < 4; i++) {
        size_t idx = aoff[i] + kc + k;
        if (ABF16)
          xv[i] = bfq2f4(*(const uint2*)((const ushort_t*)Av + idx));
        else
          xv[i] = *(const float4*)((const float*)Av + idx);
      }
      float4 w0 = wlds[(k + 0) * 16 + c0];
      float4 w1 = wlds[(k + 1) * 16 + c0];
      float4 w2 = wlds[(k + 2) * 16 + c0];
      float4 w3 = wlds[(k + 3) * 16 + c0];
#pragma unroll
      for (int i = 0; i < 4; i++) {
        acc[i].x += xv[i].x * w0.x + xv[i].y * w1.x + xv[i].z * w2.x + xv[i].w * w3.x;
        acc[i].y += xv[i].x * w0.y + xv[i].y * w1.y + xv[i].z * w2.y + xv[i].w * w3.y;
        acc[i].z += xv[i].x * w0.z + xv[i].y * w1.z + xv[i].z * w2.z + xv[i].w * w3.z;
        acc[i].w += xv[i].x * w0.w + xv[i].y * w1.w + xv[i].z * w2.w + xv[i].w * w3.w;
      }
    }
    __syncthreads();  // all waves participate (no early return above)
  }
#pragma unroll
  for (int i = 0; i < 4; i++)
    if (ok[i]) Cb[(size_t)(r0 + i) * 16 + c0] = f42bfq(acc[i]);
}

// --- aggregation: wave per node, 4 edges/wave, bf16 gather ------------------
// Lane layout: quarter = lane>>4 picks the edge of a 4-edge group, sub =
// lane&15 picks the uint2 (4 bf16 = 8 B) of the 128 B h-row.  4-way unroll
// => 16 independent 128 B gathers in flight per wave.  fp32 accumulate.
template <bool OUTBF>
__global__ __launch_bounds__(256) void agg_kernel(
    const uint2* __restrict__ h, const int* __restrict__ rowptr, const int* __restrict__ col,
    const float* __restrict__ wgt, const float* __restrict__ dis, const float* __restrict__ bias,
    void* __restrict__ outv, int N, int relu) {
  int wid = (blockIdx.x * blockDim.x + threadIdx.x) >> 6;
  if (wid >= N) return;
  int lane = threadIdx.x & 63;
  int sub = lane & 15;      // uint2 index within the 64-feature row
  int quarter = lane >> 4;  // which edge of the 4-group

  int start = rowptr[wid], end = rowptr[wid + 1];
  float di = dis[wid];

  float4 a0 = make_float4(0.f, 0.f, 0.f, 0.f), a1 = a0, a2 = a0, a3 = a0;
  {  // self-loop term (quarter 0 only; quarters are summed at the end)
    float4 self = bfq2f4(h[(size_t)wid * 16 + sub]);
    if (quarter == 0) {
      a0.x = di * di * self.x;
      a0.y = di * di * self.y;
      a0.z = di * di * self.z;
      a0.w = di * di * self.w;
    }
  }

  for (int base = start; base < end; base += 64) {
    int e = base + lane;
    int sj = 0;
    float wj = 0.f;
    if (e < end) {
      sj = col[e];
      wj = wgt[e];
    }
    int cnt = end - base;
    if (cnt > 64) cnt = 64;
    int rounds = (cnt + 3) >> 2;  // 4-edge groups in this chunk
    int t = 0;
    for (; t + 4 <= rounds; t += 4) {
      int i0 = 4 * t + quarter;
      int s0 = __shfl(sj, i0), s1 = __shfl(sj, i0 + 4), s2 = __shfl(sj, i0 + 8),
          s3 = __shfl(sj, i0 + 12);
      float w0 = __shfl(wj, i0), w1 = __shfl(wj, i0 + 4), w2 = __shfl(wj, i0 + 8),
            w3 = __shfl(wj, i0 + 12);
      float4 g0 = bfq2f4(h[(size_t)s0 * 16 + sub]);
      float4 g1 = bfq2f4(h[(size_t)s1 * 16 + sub]);
      float4 g2 = bfq2f4(h[(size_t)s2 * 16 + sub]);
      float4 g3 = bfq2f4(h[(size_t)s3 * 16 + sub]);
      a0.x += w0 * g0.x; a0.y += w0 * g0.y; a0.z += w0 * g0.z; a0.w += w0 * g0.w;
      a1.x += w1 * g1.x; a1.y += w1 * g1.y; a1.z += w1 * g1.z; a1.w += w1 * g1.w;
      a2.x += w2 * g2.x; a2.y += w2 * g2.y; a2.z += w2 * g2.z; a2.w += w2 * g2.w;
      a3.x += w3 * g3.x; a3.y += w3 * g3.y; a3.z += w3 * g3.z; a3.w += w3 * g3.w;
    }
    for (; t < rounds; t++) {
      int i0 = 4 * t + quarter;  // may exceed cnt-1 for tail quarters: wj there is 0
      int s0 = __shfl(sj, i0);
      float w0 = __shfl(wj, i0);
      float4 g0 = bfq2f4(h[(size_t)s0 * 16 + sub]);
      a0.x += w0 * g0.x; a0.y += w0 * g0.y; a0.z += w0 * g0.z; a0.w += w0 * g0.w;
    }
  }

  float sx = (a0.x + a1.x) + (a2.x + a3.x);
  float sy = (a0.y + a1.y) + (a2.y + a3.y);
  float sz = (a0.z + a1.z) + (a2.z + a3.z);
  float sw = (a0.w + a1.w) + (a2.w + a3.w);
  // fold quarters: lanes sub+16k -> lane sub
  sx += __shfl_down(sx, 32); sy += __shfl_down(sy, 32);
  sz += __shfl_down(sz, 32); sw += __shfl_down(sw, 32);
  sx += __shfl_down(sx, 16); sy += __shfl_down(sy, 16);
  sz += __shfl_down(sz, 16); sw += __shfl_down(sw, 16);
  if (quarter == 0) {
    float4 bv = ((const float4*)bias)[sub];
    float4 o = make_float4(sx + bv.x, sy + bv.y, sz + bv.z, sw + bv.w);
    if (relu) {
      o.x = fmaxf(o.x, 0.f);
      o.y = fmaxf(o.y, 0.f);
      o.z = fmaxf(o.z, 0.f);
      o.w = fmaxf(o.w, 0.f);
    }
    if (OUTBF)
      ((uint2*)outv)[(size_t)wid * 16 + sub] = f42bfq(o);
    else
      ((float4*)outv)[(size_t)wid * 16 + sub] = o;
  }
}

// ---------------------------------------------------------------------------
extern "C" void kernel_launch(void* const* d_in, const int* in_sizes, int n_in,
                              void* d_out, int out_size, void* d_ws, size_t ws_size,
                              hipStream_t stream) {
  const float* x = (const float*)d_in[0];
  const int* ei = (const int*)d_in[1];
  const float* W1 = (const float*)d_in[2];
  const float* b1 = (const float*)d_in[3];
  const float* W2 = (const float*)d_in[4];
  const float* b2 = (const float*)d_in[5];

  const int IN = 256;
  const int E = in_sizes[1] / 2;
  const int N = in_sizes[0] / IN;
  const int* src = ei;      // edge_index[0]
  const int* dst = ei + E;  // edge_index[1]
  const int nbins = (N + BIN_NODES - 1) >> BIN_SHIFT;

  // workspace carve-up (256B aligned)
  char* ws = (char*)d_ws;
  size_t off = 0;
  auto alloc = [&](size_t bytes) -> void* {
    void* p = ws + off;
    off += (bytes + 255) & ~(size_t)255;
    return p;
  };
  int* count = (int*)alloc((size_t)N * 4);
  int* rowptr = (int*)alloc((size_t)(N + 1) * 4);
  float* dis = (float*)alloc((size_t)N * 4);
  int* bsum = (int*)alloc(4096);
  int* binCnt = (int*)alloc(MAX_BINS * 4);
  int* binStart = (int*)alloc((MAX_BINS + 1) * 4);
  int* binCursor = (int*)alloc(MAX_BINS * 4);
  int* col = (int*)alloc((size_t)E * 4);
  float* wgt = (float*)alloc((size_t)E * 4);
  uint2* out1 = (uint2*)alloc((size_t)N * 64 * 2);  // bf16 layer-1 activations
  // binbuf (E packed u32) aliases h (N*64 bf16): binbuf dead once csr_fill is
  // done, h first written by gemm1 afterwards.  12.8 MB each.
  size_t big = ((size_t)E * 4 > (size_t)N * 128) ? (size_t)E * 4 : (size_t)N * 128;
  unsigned* binbuf = (unsigned*)alloc(big);
  uint2* h = (uint2*)binbuf;
  float* outf = (float*)d_out;

  const int tb = 256;
  const int nb = (N + 1023) / 1024;

  zero_int<<<(nbins + tb - 1) / tb, tb, 0, stream>>>(binCnt, nbins);
  bin_count<<<1024, 256, 0, stream>>>(dst, E, nbins, binCnt);
  bin_scan<<<1, 256, 0, stream>>>(binCnt, nbins, E, binStart, binCursor);
  bin_fill<<<512, 256, 0, stream>>>(src, dst, E, nbins, binCursor, binbuf);
  node_count_dis<<<nbins, 256, 0, stream>>>(binbuf, binStart, N, count, dis);
  scan_partial<<<nb, 256, 0, stream>>>(count, bsum, N);
  scan_blocksums<<<1, 256, 0, stream>>>(bsum, nb);
  scan_final<<<nb, 256, 0, stream>>>(count, bsum, rowptr, N, E);
  csr_fill<<<nbins, 256, 0, stream>>>(binbuf, binStart, rowptr, dis, N, col, wgt);

  gemm64<256, false><<<(N + 63) / 64, 256, 0, stream>>>(x, W1, h, N);
  agg_kernel<true><<<(N + 3) / 4, 256, 0, stream>>>(h, rowptr, col, wgt, dis, b1, out1, N, 1);
  gemm64<64, true><<<(N + 63) / 64, 256, 0, stream>>>(out1, W2, h, N);
  agg_kernel<false><<<(N + 3) / 4, 256, 0, stream>>>(h, rowptr, col, wgt, dis, b2, outf, N, 0);
}

// Round 6
// 508.118 us; speedup vs baseline: 1.2724x; 1.0639x over previous
//
#include <hip/hip_runtime.h>
#include <cstdint>
#include <cstddef>

// ---------------------------------------------------------------------------
// GCN 2-layer encoder.  Pipeline per launch (11 dispatches):
//   1. bin_count: 782-bin histogram of dst>>7
//   2. bin_scan:  binStart/binCursor (fine) + superCursor (dst>>11, 49 bins)
//   3. super_fill: partition edges into super-bins, LDS tile staging ->
//      ~170 B chunky flushes (kills the 4 B random-scatter of round 5)
//   4. fine_fill:  scatter each ~200 KB super-segment into its 16 fine bins
//      (random writes confined to L2-resident window)
//   5. node_count_dis: per-fine-bin LDS degree count -> count[], dis[]
//   6. bin_csr: per-bin LDS scan of 128 counts -> rowptr + col scatter
//      (replaces global N-scan x3 + csr_fill; no wgt array at all)
//   7. gemm1 -> h1 (bf16)   8. agg1 -> out1 (bf16, relu)
//   9. gemm2 -> h2 (bf16)  10. agg2 -> d_out (fp32)
// agg computes w on the fly: out = di * (sum_j dis[src_j]*h_j + di*h_self).
// ---------------------------------------------------------------------------

#define BIN_SHIFT 7
#define BIN_NODES 128
#define MAX_BINS 1024
#define SUP_SHIFT 11
#define FINE_PER_SUP 16
#define NSUP_MAX 64
#define SCAP 56  // per-super staging capacity per 2048-edge tile (mean 42)
#define SRC_BITS 17
#define SRC_MASK ((1 << SRC_BITS) - 1)

typedef unsigned short ushort_t;

__device__ __forceinline__ float4 bfq2f4(uint2 p) {  // 4 packed bf16 -> fp32 (exact)
  float4 r;
  r.x = __uint_as_float(p.x << 16);
  r.y = __uint_as_float(p.x & 0xFFFF0000u);
  r.z = __uint_as_float(p.y << 16);
  r.w = __uint_as_float(p.y & 0xFFFF0000u);
  return r;
}
__device__ __forceinline__ unsigned f2bf(float f) {  // fp32 -> bf16 bits, RNE
  unsigned u = __float_as_uint(f);
  return (u + 0x7FFFu + ((u >> 16) & 1u)) >> 16;
}
__device__ __forceinline__ uint2 f42bfq(float4 f) {
  uint2 r;
  r.x = f2bf(f.x) | (f2bf(f.y) << 16);
  r.y = f2bf(f.z) | (f2bf(f.w) << 16);
  return r;
}

__global__ void zero_int(int* __restrict__ p, int n) {
  int i = blockIdx.x * blockDim.x + threadIdx.x;
  if (i < n) p[i] = 0;
}

// --- pass 1: fine histogram -------------------------------------------------
__global__ __launch_bounds__(256) void bin_count(const int* __restrict__ dst, int E, int nbins,
                                                 int* __restrict__ binCnt) {
  __shared__ int h[MAX_BINS];
  for (int i = threadIdx.x; i < nbins; i += 256) h[i] = 0;
  __syncthreads();
  int stride = gridDim.x * 256;
  for (int e = blockIdx.x * 256 + threadIdx.x; e < E; e += stride)
    atomicAdd(&h[dst[e] >> BIN_SHIFT], 1);
  __syncthreads();
  for (int i = threadIdx.x; i < nbins; i += 256)
    if (h[i]) atomicAdd(&binCnt[i], h[i]);
}

// --- pass 2: scan fine bins; derive super cursors ---------------------------
__global__ __launch_bounds__(256) void bin_scan(const int* __restrict__ binCnt, int nbins, int E,
                                                int* __restrict__ binStart,
                                                int* __restrict__ binCursor,
                                                int* __restrict__ supCursor) {
  __shared__ int s[256];
  int t = threadIdx.x;
  int c[4];
  int sum = 0;
#pragma unroll
  for (int i = 0; i < 4; i++) {
    int idx = t * 4 + i;
    c[i] = (idx < nbins) ? binCnt[idx] : 0;
    sum += c[i];
  }
  int v = sum;
  s[t] = v;
  __syncthreads();
  for (int d = 1; d < 256; d <<= 1) {
    int add = (t >= d) ? s[t - d] : 0;
    __syncthreads();
    s[t] += add;
    __syncthreads();
  }
  int run = s[t] - v;  // exclusive prefix
#pragma unroll
  for (int i = 0; i < 4; i++) {
    int idx = t * 4 + i;
    if (idx < nbins) {
      binStart[idx] = run;
      binCursor[idx] = run;
      if ((idx & (FINE_PER_SUP - 1)) == 0) supCursor[idx >> 4] = run;  // super segment start
      run += c[i];
    }
  }
  if (t == 0) binStart[nbins] = E;
}

// --- pass 3: partition into super-bins with LDS tile staging ----------------
// Tile of 2048 edges; per super-bin avg 42 entries -> flushed as ~170 B
// contiguous chunks. Rare overflow (>SCAP) spills as direct global writes.
__global__ __launch_bounds__(256) void super_fill(const int* __restrict__ src,
                                                  const int* __restrict__ dst, int E, int nsup,
                                                  int* __restrict__ supCursor,
                                                  unsigned* __restrict__ supbuf) {
  __shared__ unsigned stage[NSUP_MAX * SCAP];
  __shared__ int lcnt[NSUP_MAX], lbase[NSUP_MAX], lscan[NSUP_MAX + 1];
  int chunk = (E + gridDim.x - 1) / gridDim.x;
  int c0 = blockIdx.x * chunk;
  int c1 = min(E, c0 + chunk);
  for (int t0 = c0; t0 < c1; t0 += 2048) {
    int t1 = min(c1, t0 + 2048);
    if (threadIdx.x < nsup) lcnt[threadIdx.x] = 0;
    __syncthreads();
    for (int e = t0 + threadIdx.x; e < t1; e += 256) {
      int d = dst[e];
      int sb = d >> SUP_SHIFT;
      unsigned v = ((unsigned)(d & ((1 << SUP_SHIFT) - 1)) << SRC_BITS) | (unsigned)src[e];
      int idx = atomicAdd(&lcnt[sb], 1);
      if (idx < SCAP)
        stage[sb * SCAP + idx] = v;
      else {  // rare overflow: direct write
        int g = atomicAdd(&supCursor[sb], 1);
        supbuf[g] = v;
      }
    }
    __syncthreads();
    if (threadIdx.x < nsup) {
      int c = min(lcnt[threadIdx.x], SCAP);
      lcnt[threadIdx.x] = c;
      lbase[threadIdx.x] = c ? atomicAdd(&supCursor[threadIdx.x], c) : 0;
    }
    __syncthreads();
    if (threadIdx.x == 0) {  // tiny serial scan over <=64 bins
      int r = 0;
      for (int i = 0; i < nsup; i++) {
        lscan[i] = r;
        r += lcnt[i];
      }
      lscan[nsup] = r;
    }
    __syncthreads();
    int total = lscan[nsup];
    for (int j = threadIdx.x; j < total; j += 256) {
      int lo = 0, hi = nsup;  // binary search: lscan[lo] <= j < lscan[lo+1]
      while (hi - lo > 1) {
        int mid = (lo + hi) >> 1;
        if (lscan[mid] <= j)
          lo = mid;
        else
          hi = mid;
      }
      int off = j - lscan[lo];
      supbuf[lbase[lo] + off] = stage[lo * SCAP + off];
    }
    __syncthreads();
  }
}

// --- pass 4: scatter super-segment into its 16 fine bins (L2 window) --------
__global__ __launch_bounds__(256) void fine_fill(const unsigned* __restrict__ supbuf,
                                                 const int* __restrict__ binStart, int nbins,
                                                 int* __restrict__ binCursor,
                                                 unsigned* __restrict__ binbuf) {
  __shared__ int lcnt[FINE_PER_SUP], lbase[FINE_PER_SUP];
  int sb = blockIdx.x >> 3, p = blockIdx.x & 7;
  int seg0 = binStart[sb << 4];
  int seg1 = binStart[min((sb + 1) << 4, nbins)];
  int part = (seg1 - seg0 + 7) >> 3;
  int c0 = seg0 + p * part;
  int c1 = min(seg1, c0 + part);
  if (threadIdx.x < FINE_PER_SUP) lcnt[threadIdx.x] = 0;
  __syncthreads();
  for (int i = c0 + threadIdx.x; i < c1; i += 256) atomicAdd(&lcnt[supbuf[i] >> 24], 1);
  __syncthreads();
  if (threadIdx.x < FINE_PER_SUP) {
    int c = lcnt[threadIdx.x];
    lbase[threadIdx.x] = c ? atomicAdd(&binCursor[(sb << 4) + threadIdx.x], c) : 0;
    lcnt[threadIdx.x] = 0;
  }
  __syncthreads();
  for (int i = c0 + threadIdx.x; i < c1; i += 256) {
    unsigned v = supbuf[i];
    unsigned dls = v >> SRC_BITS;  // 11-bit dst-local-to-super
    int f = dls >> BIN_SHIFT;      // fine bin within super
    unsigned vf = ((dls & (BIN_NODES - 1)) << SRC_BITS) | (v & SRC_MASK);
    int idx = lbase[f] + atomicAdd(&lcnt[f], 1);
    binbuf[idx] = vf;
  }
}

// --- pass 5: per-bin node degree + dis --------------------------------------
__global__ __launch_bounds__(256) void node_count_dis(const unsigned* __restrict__ binbuf,
                                                      const int* __restrict__ binStart, int N,
                                                      int* __restrict__ count,
                                                      float* __restrict__ dis) {
  __shared__ int cnt[BIN_NODES];
  int b = blockIdx.x;
  int nodeBase = b << BIN_SHIFT;
  if (threadIdx.x < BIN_NODES) cnt[threadIdx.x] = 0;
  __syncthreads();
  int s0 = binStart[b], s1 = binStart[b + 1];
  for (int i = s0 + threadIdx.x; i < s1; i += 256) atomicAdd(&cnt[binbuf[i] >> SRC_BITS], 1);
  __syncthreads();
  if (threadIdx.x < BIN_NODES) {
    int node = nodeBase + threadIdx.x;
    if (node < N) {
      int c = cnt[threadIdx.x];
      count[node] = c;
      dis[node] = rsqrtf((float)(c + 1));  // +1 self loop
    }
  }
}

// --- pass 6: fused per-bin scan + CSR col scatter ---------------------------
__global__ __launch_bounds__(256) void bin_csr(const unsigned* __restrict__ binbuf,
                                               const int* __restrict__ binStart,
                                               const int* __restrict__ count, int N, int E,
                                               int* __restrict__ rowptr, int* __restrict__ col) {
  __shared__ int cur[BIN_NODES];
  __shared__ int pref[BIN_NODES];
  int b = blockIdx.x, t = threadIdx.x;
  int nodeBase = b << BIN_SHIFT;
  int c = 0;
  if (t < BIN_NODES) {
    int node = nodeBase + t;
    c = (node < N) ? count[node] : 0;
    pref[t] = c;
  }
  __syncthreads();
  for (int d = 1; d < BIN_NODES; d <<= 1) {  // inclusive scan over 128
    int add = (t < BIN_NODES && t >= d) ? pref[t - d] : 0;
    __syncthreads();
    if (t < BIN_NODES) pref[t] += add;
    __syncthreads();
  }
  int s0 = binStart[b];
  if (t < BIN_NODES) {
    int node = nodeBase + t;
    if (node < N) {
      int ex = s0 + pref[t] - c;  // exclusive prefix + segment base
      rowptr[node] = ex;
      cur[t] = ex;
    }
  }
  if (b == 0 && t == 255) rowptr[N] = E;
  __syncthreads();
  int s1 = binStart[b + 1];
  for (int i = s0 + t; i < s1; i += 256) {
    unsigned v = binbuf[i];
    int slot = atomicAdd(&cur[v >> SRC_BITS], 1);
    col[slot] = v & SRC_MASK;
  }
}

// --- GEMM: Cbf16[M][64] = A[M][K] @ W[K][64], W staged in LDS ---------------
template <int K, bool ABF16>
__global__ __launch_bounds__(256, 4) void gemm64(const void* __restrict__ Av,
                                                 const float* __restrict__ W,
                                                 uint2* __restrict__ Cb, int M) {
  constexpr int CHUNK = (K > 128) ? 128 : K;
  __shared__ float4 wlds[CHUNK * 16];

  const int c0 = threadIdx.x & 15;
  const int rq = threadIdx.x >> 4;
  const int r0 = blockIdx.x * 64 + rq * 4;

  float4 acc[4];
#pragma unroll
  for (int i = 0; i < 4; i++) acc[i] = make_float4(0.f, 0.f, 0.f, 0.f);
  size_t aoff[4];
  bool ok[4];
#pragma unroll
  for (int i = 0; i < 4; i++) {
    int r = r0 + i;
    ok[i] = (r < M);
    aoff[i] = (size_t)(ok[i] ? r : (M - 1)) * K;
  }

  for (int kc = 0; kc < K; kc += CHUNK) {
    {
      const float4* W4 = (const float4*)W + (size_t)kc * 16;
      for (int i = threadIdx.x; i < CHUNK * 16; i += 256) wlds[i] = W4[i];
    }
    __syncthreads();

#pragma unroll 2
    for (int k = 0; k < CHUNK; k += 4) {
      float4 xv[4];
#pragma unroll
      for (int i = 0; i < 4; i++) {
        size_t idx = aoff[i] + kc + k;
        if (ABF16)
          xv[i] = bfq2f4(*(const uint2*)((const ushort_t*)Av + idx));
        else
          xv[i] = *(const float4*)((const float*)Av + idx);
      }
      float4 w0 = wlds[(k + 0) * 16 + c0];
      float4 w1 = wlds[(k + 1) * 16 + c0];
      float4 w2 = wlds[(k + 2) * 16 + c0];
      float4 w3 = wlds[(k + 3) * 16 + c0];
#pragma unroll
      for (int i = 0; i < 4; i++) {
        acc[i].x += xv[i].x * w0.x + xv[i].y * w1.x + xv[i].z * w2.x + xv[i].w * w3.x;
        acc[i].y += xv[i].x * w0.y + xv[i].y * w1.y + xv[i].z * w2.y + xv[i].w * w3.y;
        acc[i].z += xv[i].x * w0.z + xv[i].y * w1.z + xv[i].z * w2.z + xv[i].w * w3.z;
        acc[i].w += xv[i].x * w0.w + xv[i].y * w1.w + xv[i].z * w2.w + xv[i].w * w3.w;
      }
    }
    __syncthreads();
  }
#pragma unroll
  for (int i = 0; i < 4; i++)
    if (ok[i]) Cb[(size_t)(r0 + i) * 16 + c0] = f42bfq(acc[i]);
}

// --- aggregation: wave per node, 4 edges/wave, bf16 gather, on-the-fly w ----
// w_edge = dis[src]; final sum scaled by di = dis[dst] once:
//   out = di * ( sum_j dis[src_j]*h_j + di*h_self ) + bias
template <bool OUTBF>
__global__ __launch_bounds__(256) void agg_kernel(
    const uint2* __restrict__ h, const int* __restrict__ rowptr, const int* __restrict__ col,
    const float* __restrict__ dis, const float* __restrict__ bias, void* __restrict__ outv,
    int N, int relu) {
  int wid = (blockIdx.x * blockDim.x + threadIdx.x) >> 6;
  if (wid >= N) return;
  int lane = threadIdx.x & 63;
  int sub = lane & 15;
  int quarter = lane >> 4;

  int start = rowptr[wid], end = rowptr[wid + 1];
  float di = dis[wid];

  float4 a0 = make_float4(0.f, 0.f, 0.f, 0.f), a1 = a0, a2 = a0, a3 = a0;
  {  // self-loop: di*h_self (quarter 0 only); final *di makes it di^2
    float4 self = bfq2f4(h[(size_t)wid * 16 + sub]);
    if (quarter == 0) {
      a0.x = di * self.x;
      a0.y = di * self.y;
      a0.z = di * self.z;
      a0.w = di * self.w;
    }
  }

  for (int base = start; base < end; base += 64) {
    int e = base + lane;
    int sj = 0;
    float wj = 0.f;
    if (e < end) {
      sj = col[e];
      wj = dis[sj];  // L2-resident 400 KB table (replaces wgt stream)
    }
    int cnt = end - base;
    if (cnt > 64) cnt = 64;
    int rounds = (cnt + 3) >> 2;
    int t = 0;
    for (; t + 4 <= rounds; t += 4) {
      int i0 = 4 * t + quarter;
      int s0 = __shfl(sj, i0), s1 = __shfl(sj, i0 + 4), s2 = __shfl(sj, i0 + 8),
          s3 = __shfl(sj, i0 + 12);
      float w0 = __shfl(wj, i0), w1 = __shfl(wj, i0 + 4), w2 = __shfl(wj, i0 + 8),
            w3 = __shfl(wj, i0 + 12);
      float4 g0 = bfq2f4(h[(size_t)s0 * 16 + sub]);
      float4 g1 = bfq2f4(h[(size_t)s1 * 16 + sub]);
      float4 g2 = bfq2f4(h[(size_t)s2 * 16 + sub]);
      float4 g3 = bfq2f4(h[(size_t)s3 * 16 + sub]);
      a0.x += w0 * g0.x; a0.y += w0 * g0.y; a0.z += w0 * g0.z; a0.w += w0 * g0.w;
      a1.x += w1 * g1.x; a1.y += w1 * g1.y; a1.z += w1 * g1.z; a1.w += w1 * g1.w;
      a2.x += w2 * g2.x; a2.y += w2 * g2.y; a2.z += w2 * g2.z; a2.w += w2 * g2.w;
      a3.x += w3 * g3.x; a3.y += w3 * g3.y; a3.z += w3 * g3.z; a3.w += w3 * g3.w;
    }
    for (; t < rounds; t++) {
      int i0 = 4 * t + quarter;  // tail quarters past cnt have wj==0
      int s0 = __shfl(sj, i0);
      float w0 = __shfl(wj, i0);
      float4 g0 = bfq2f4(h[(size_t)s0 * 16 + sub]);
      a0.x += w0 * g0.x; a0.y += w0 * g0.y; a0.z += w0 * g0.z; a0.w += w0 * g0.w;
    }
  }

  float sx = (a0.x + a1.x) + (a2.x + a3.x);
  float sy = (a0.y + a1.y) + (a2.y + a3.y);
  float sz = (a0.z + a1.z) + (a2.z + a3.z);
  float sw = (a0.w + a1.w) + (a2.w + a3.w);
  sx += __shfl_down(sx, 32); sy += __shfl_down(sy, 32);
  sz += __shfl_down(sz, 32); sw += __shfl_down(sw, 32);
  sx += __shfl_down(sx, 16); sy += __shfl_down(sy, 16);
  sz += __shfl_down(sz, 16); sw += __shfl_down(sw, 16);
  if (quarter == 0) {
    float4 bv = ((const float4*)bias)[sub];
    float4 o = make_float4(di * sx + bv.x, di * sy + bv.y, di * sz + bv.z, di * sw + bv.w);
    if (relu) {
      o.x = fmaxf(o.x, 0.f);
      o.y = fmaxf(o.y, 0.f);
      o.z = fmaxf(o.z, 0.f);
      o.w = fmaxf(o.w, 0.f);
    }
    if (OUTBF)
      ((uint2*)outv)[(size_t)wid * 16 + sub] = f42bfq(o);
    else
      ((float4*)outv)[(size_t)wid * 16 + sub] = o;
  }
}

// ---------------------------------------------------------------------------
extern "C" void kernel_launch(void* const* d_in, const int* in_sizes, int n_in,
                              void* d_out, int out_size, void* d_ws, size_t ws_size,
                              hipStream_t stream) {
  const float* x = (const float*)d_in[0];
  const int* ei = (const int*)d_in[1];
  const float* W1 = (const float*)d_in[2];
  const float* b1 = (const float*)d_in[3];
  const float* W2 = (const float*)d_in[4];
  const float* b2 = (const float*)d_in[5];

  const int IN = 256;
  const int E = in_sizes[1] / 2;
  const int N = in_sizes[0] / IN;
  const int* src = ei;
  const int* dst = ei + E;
  const int nbins = (N + BIN_NODES - 1) >> BIN_SHIFT;
  const int nsup = (N + (1 << SUP_SHIFT) - 1) >> SUP_SHIFT;

  // workspace carve-up (256B aligned)
  char* ws = (char*)d_ws;
  size_t off = 0;
  auto alloc = [&](size_t bytes) -> void* {
    void* p = ws + off;
    off += (bytes + 255) & ~(size_t)255;
    return p;
  };
  int* count = (int*)alloc((size_t)N * 4);
  int* rowptr = (int*)alloc((size_t)(N + 1) * 4);
  float* dis = (float*)alloc((size_t)N * 4);
  int* binCnt = (int*)alloc(MAX_BINS * 4);
  int* binStart = (int*)alloc((MAX_BINS + 1) * 4);
  int* binCursor = (int*)alloc(MAX_BINS * 4);
  int* supCursor = (int*)alloc(NSUP_MAX * 4);
  int* col = (int*)alloc((size_t)E * 4);                // 12.8 MB; written by bin_csr
  unsigned* supbuf = (unsigned*)col;                    // alias: dead before col written
  uint2* out1 = (uint2*)alloc((size_t)N * 64 * 2);      // bf16 layer-1 activations
  size_t big = ((size_t)E * 4 > (size_t)N * 128) ? (size_t)E * 4 : (size_t)N * 128;
  unsigned* binbuf = (unsigned*)alloc(big);             // aliases h (dead before gemm1)
  uint2* h = (uint2*)binbuf;
  float* outf = (float*)d_out;

  zero_int<<<(nbins + 255) / 256, 256, 0, stream>>>(binCnt, nbins);
  bin_count<<<1024, 256, 0, stream>>>(dst, E, nbins, binCnt);
  bin_scan<<<1, 256, 0, stream>>>(binCnt, nbins, E, binStart, binCursor, supCursor);
  super_fill<<<512, 256, 0, stream>>>(src, dst, E, nsup, supCursor, supbuf);
  fine_fill<<<nsup * 8, 256, 0, stream>>>(supbuf, binStart, nbins, binCursor, binbuf);
  node_count_dis<<<nbins, 256, 0, stream>>>(binbuf, binStart, N, count, dis);
  bin_csr<<<nbins, 256, 0, stream>>>(binbuf, binStart, count, N, E, rowptr, col);

  gemm64<256, false><<<(N + 63) / 64, 256, 0, stream>>>(x, W1, h, N);
  agg_kernel<true><<<(N + 3) / 4, 256, 0, stream>>>(h, rowptr, col, dis, b1, out1, N, 1);
  gemm64<64, true><<<(N + 63) / 64, 256, 0, stream>>>(out1, W2, h, N);
  agg_kernel<false><<<(N + 3) / 4, 256, 0, stream>>>(h, rowptr, col, dis, b2, outf, N, 0);
}